// Round 1
// baseline (108.089 us; speedup 1.0000x reference)
//
#include <hip/hip_runtime.h>
#include <hip/hip_bf16.h>

#define LRELU_ALPHA 0.2f

typedef __attribute__((ext_vector_type(8))) short short8;
typedef __attribute__((ext_vector_type(4))) float f32x4;

__device__ __forceinline__ float bf2f(unsigned short u) {
  union { unsigned int i; float f; } x;
  x.i = ((unsigned int)u) << 16;
  return x.f;
}

// ---------------- K0a: Wt[f][t] = bf16(W[t][f]) ----------------
// grid 256 (t), block 256 (f). Reads coalesced over f, tiny scatter writes.
__global__ __launch_bounds__(256) void k0_wt(const float* __restrict__ W,
                                             __hip_bfloat16* __restrict__ Wt) {
  int t = blockIdx.x, f = threadIdx.x;
  Wt[f * 256 + t] = __float2bfloat16(W[t * 256 + f]);
}

// ---------------- K0b: Wa1[t] = sum_f W[t][f]*a1[f], Wa2 likewise ----------
// grid 256 (t), block 64 (one wave).
__global__ __launch_bounds__(64) void k0_wa(const float* __restrict__ W,
                                            const float* __restrict__ a,
                                            float* __restrict__ Wa) {
  int t = blockIdx.x, lane = threadIdx.x;
  float4 wv = *reinterpret_cast<const float4*>(W + t * 256 + lane * 4);
  float4 a1 = *reinterpret_cast<const float4*>(a + lane * 4);
  float4 a2 = *reinterpret_cast<const float4*>(a + 256 + lane * 4);
  float p1 = wv.x * a1.x + wv.y * a1.y + wv.z * a1.z + wv.w * a1.w;
  float p2 = wv.x * a2.x + wv.y * a2.y + wv.z * a2.z + wv.w * a2.w;
  #pragma unroll
  for (int off = 32; off; off >>= 1) {
    p1 += __shfl_down(p1, off);
    p2 += __shfl_down(p2, off);
  }
  if (lane == 0) { Wa[t] = p1; Wa[256 + t] = p2; }
}

// ---------------- K0c: adj_norm (7x7) ----------------
__global__ __launch_bounds__(64) void k0_adj(const float* __restrict__ B,
                                             float* __restrict__ adjn) {
  int t = threadIdx.x;
  float v = 0.f;
  if (t < 49) v = B[t] + (((t / 7) == (t % 7)) ? 1.f : 0.f);
  float mn = (t < 49) ? v : 1e30f;
  float mx = (t < 49) ? v : -1e30f;
  #pragma unroll
  for (int off = 32; off; off >>= 1) {
    mn = fminf(mn, __shfl_xor(mn, off));
    mx = fmaxf(mx, __shfl_xor(mx, off));
  }
  float scaled = (v - mn) / (mx - mn);
  __shared__ float adj[49];
  __shared__ float dis[7];
  if (t < 49) adj[t] = scaled;
  __syncthreads();
  if (t < 7) {
    float s = 0.f;
    #pragma unroll
    for (int j = 0; j < 7; ++j) s += adj[t * 7 + j];
    dis[t] = 1.0f / sqrtf(s);
  }
  __syncthreads();
  if (t < 49) adjn[t] = adj[t] * dis[t / 7] * dis[t % 7];
}

// ---------------- K1: Wh = h^T @ W (bf16 MFMA) + s1/s2 epilogue -------------
// grid 1024: n = blk>>4, c-block = blk&15 (16 c per block).
// M = 112 rows (m = c_local*7 + v), K = T = 256, Nf = F = 256.
// LDS A tile [112][264] bf16 (pad +8 -> 2-way-free ds_read_b128).
__global__ __launch_bounds__(256) void k1_gemm(const float* __restrict__ h,
                                               const __hip_bfloat16* __restrict__ Wt,
                                               const float* __restrict__ Wa,
                                               __hip_bfloat16* __restrict__ Wh,
                                               float* __restrict__ s1g,
                                               float* __restrict__ s2g) {
  __shared__ __hip_bfloat16 As[112][264];  // 59.1 KB
  const int blk = blockIdx.x;
  const int n = blk >> 4, cb = blk & 15;
  const int tid = threadIdx.x;

  // ---- stage: h[n][cb*16..+15][t][v] (contiguous 28672 floats) -> As[c*7+v][t]
  const float4* src =
      reinterpret_cast<const float4*>(h + (size_t)(n * 256 + cb * 16) * 1792);
  #pragma unroll
  for (int it = 0; it < 28; ++it) {
    int idx4 = tid + it * 256;
    float4 val = src[idx4];
    int base = idx4 * 4;
    const float* vp = reinterpret_cast<const float*>(&val);
    #pragma unroll
    for (int q = 0; q < 4; ++q) {
      int idx = base + q;
      int c = idx / 1792;
      int r = idx - c * 1792;
      int t = r / 7;
      int v = r - t * 7;
      As[c * 7 + v][t] = __float2bfloat16(vp[q]);
    }
  }
  __syncthreads();

  const int lane = tid & 63, wave = tid >> 6;
  const int lr = lane & 15, lk = lane >> 4;
  const int f_base = wave * 64;  // each wave owns 64 f-columns (4 f-tiles)

  f32x4 acc[7][4];
  #pragma unroll
  for (int mt = 0; mt < 7; ++mt)
    #pragma unroll
    for (int ft = 0; ft < 4; ++ft) acc[mt][ft] = (f32x4){0.f, 0.f, 0.f, 0.f};

  const short* WtS = reinterpret_cast<const short*>(Wt);
  const short* AsS = reinterpret_cast<const short*>(&As[0][0]);

  for (int k0 = 0; k0 < 256; k0 += 32) {
    short8 b[4];
    #pragma unroll
    for (int ft = 0; ft < 4; ++ft)
      b[ft] = *reinterpret_cast<const short8*>(
          WtS + (f_base + ft * 16 + lr) * 256 + k0 + lk * 8);
    #pragma unroll
    for (int mt = 0; mt < 7; ++mt) {
      short8 afrag = *reinterpret_cast<const short8*>(
          AsS + (mt * 16 + lr) * 264 + k0 + lk * 8);
      #pragma unroll
      for (int ft = 0; ft < 4; ++ft)
        acc[mt][ft] = __builtin_amdgcn_mfma_f32_16x16x32_bf16(afrag, b[ft],
                                                              acc[mt][ft], 0, 0, 0);
    }
  }

  // ---- store Wh[n][c][v][f] bf16. C/D: col=lane&15, row=(lane>>4)*4+j
  #pragma unroll
  for (int mt = 0; mt < 7; ++mt) {
    #pragma unroll
    for (int j = 0; j < 4; ++j) {
      int m = mt * 16 + lk * 4 + j;
      int cl = m / 7;
      int v = m - cl * 7;
      __hip_bfloat16* dst =
          Wh + (size_t)((n * 256 + cb * 16 + cl) * 7 + v) * 256 + f_base + lr;
      #pragma unroll
      for (int ft = 0; ft < 4; ++ft)
        dst[ft * 16] = __float2bfloat16(acc[mt][ft][j]);
    }
  }

  // ---- s1/s2 epilogue: s[m] = sum_t As[m][t] * Wa{1,2}[t], 16-lane groups
  const int gid = tid >> 4;  // 0..15, group of 16 lanes
  const int fl = tid & 15;
  float wa1[16], wa2[16];
  #pragma unroll
  for (int q = 0; q < 16; ++q) {
    wa1[q] = Wa[fl * 16 + q];
    wa2[q] = Wa[256 + fl * 16 + q];
  }
  #pragma unroll
  for (int k = 0; k < 7; ++k) {
    int m = k * 16 + gid;  // covers 0..111
    short8 r0 = *reinterpret_cast<const short8*>(AsS + m * 264 + fl * 16);
    short8 r1 = *reinterpret_cast<const short8*>(AsS + m * 264 + fl * 16 + 8);
    float p1 = 0.f, p2 = 0.f;
    #pragma unroll
    for (int q = 0; q < 8; ++q) {
      float x = bf2f((unsigned short)r0[q]);
      p1 += x * wa1[q];
      p2 += x * wa2[q];
      float y = bf2f((unsigned short)r1[q]);
      p1 += y * wa1[8 + q];
      p2 += y * wa2[8 + q];
    }
    #pragma unroll
    for (int off = 1; off <= 8; off <<= 1) {
      p1 += __shfl_xor(p1, off);
      p2 += __shfl_xor(p2, off);
    }
    if (fl == 0) {
      int cl = m / 7, v = m - cl * 7;
      int c = cb * 16 + cl;
      s1g[(n * 7 + v) * 256 + c] = p1;
      s2g[(n * 7 + v) * 256 + c] = p2;
    }
  }
}

// ---------------- K2: softmax over c -> att[n][c][i*7+j] ----------------
// grid 64 (n), block 256 (4 waves); wave handles (i,j) pairs round-robin.
__global__ __launch_bounds__(256) void k2_soft(const float* __restrict__ s1g,
                                               const float* __restrict__ s2g,
                                               float* __restrict__ att) {
  __shared__ float s1L[1792], s2L[1792];
  const int n = blockIdx.x, tid = threadIdx.x;
  for (int idx = tid; idx < 1792; idx += 256) {
    s1L[idx] = s1g[n * 1792 + idx];
    s2L[idx] = s2g[n * 1792 + idx];
  }
  __syncthreads();
  const int lane = tid & 63, wave = tid >> 6;
  for (int p = wave; p < 49; p += 4) {
    int i = p / 7, j = p - i * 7;
    float ex[4];
    float mx = -1e30f;
    #pragma unroll
    for (int q = 0; q < 4; ++q) {
      int c = lane + q * 64;
      float e = s1L[i * 256 + c] + s2L[j * 256 + c];
      e = (e > 0.f) ? e : LRELU_ALPHA * e;
      ex[q] = e;
      mx = fmaxf(mx, e);
    }
    #pragma unroll
    for (int off = 32; off; off >>= 1) mx = fmaxf(mx, __shfl_xor(mx, off));
    float sm = 0.f;
    #pragma unroll
    for (int q = 0; q < 4; ++q) {
      ex[q] = __expf(ex[q] - mx);
      sm += ex[q];
    }
    #pragma unroll
    for (int off = 32; off; off >>= 1) sm += __shfl_xor(sm, off);
    float inv = 1.0f / sm;
    #pragma unroll
    for (int q = 0; q < 4; ++q) {
      int c = lane + q * 64;
      att[((size_t)n * 256 + c) * 49 + p] = ex[q] * inv;
    }
  }
}

// ---------------- K3: out[n,c,f,v] = elu( sum_j Wh[n,c,j,f] * M[j,v] ) ------
// M[j,v] = sum_i att[n,c,i*7+j] * adjn[i,v].  grid 16384 (n,c), block 256 (f).
__global__ __launch_bounds__(256) void k3_out(const __hip_bfloat16* __restrict__ Wh,
                                              const float* __restrict__ att,
                                              const float* __restrict__ adjn,
                                              float* __restrict__ out) {
  __shared__ float attL[49], adjL[49], M[49];
  __shared__ float outL[1792];
  const int blk = blockIdx.x;
  const int n = blk >> 8, c = blk & 255;
  const int tid = threadIdx.x;
  if (tid < 49) {
    attL[tid] = att[((size_t)n * 256 + c) * 49 + tid];
    adjL[tid] = adjn[tid];
  }
  __syncthreads();
  if (tid < 49) {
    int j = tid / 7, v = tid - (tid / 7) * 7;
    float s = 0.f;
    #pragma unroll
    for (int i = 0; i < 7; ++i) s += attL[i * 7 + j] * adjL[i * 7 + v];
    M[tid] = s;
  }
  __syncthreads();
  const unsigned short* WhS = reinterpret_cast<const unsigned short*>(Wh) +
                              ((size_t)n * 256 + c) * 1792 + tid;
  float wh[7];
  #pragma unroll
  for (int j = 0; j < 7; ++j) wh[j] = bf2f(WhS[j * 256]);
  #pragma unroll
  for (int v = 0; v < 7; ++v) {
    float o = 0.f;
    #pragma unroll
    for (int j = 0; j < 7; ++j) o += wh[j] * M[j * 7 + v];
    o = (o > 0.f) ? o : (__expf(o) - 1.f);
    outL[tid * 7 + v] = o;
  }
  __syncthreads();
  float* dst = out + (size_t)(n * 256 + c) * 1792;
  for (int idx = tid; idx < 1792; idx += 256) dst[idx] = outL[idx];
}

extern "C" void kernel_launch(void* const* d_in, const int* in_sizes, int n_in,
                              void* d_out, int out_size, void* d_ws, size_t ws_size,
                              hipStream_t stream) {
  const float* h = (const float*)d_in[0];
  const float* W = (const float*)d_in[1];
  const float* a = (const float*)d_in[2];
  const float* B = (const float*)d_in[3];
  float* out = (float*)d_out;
  char* ws = (char*)d_ws;

  // workspace layout (bytes):
  __hip_bfloat16* Wt = (__hip_bfloat16*)(ws + 0);        // 131072
  float* adjn = (float*)(ws + 131072);                   // 256
  float* Wa   = (float*)(ws + 131328);                   // 2048
  float* s1g  = (float*)(ws + 133376);                   // 458752
  float* s2g  = (float*)(ws + 592128);                   // 458752
  float* att  = (float*)(ws + 1050880);                  // 3211264
  __hip_bfloat16* Wh = (__hip_bfloat16*)(ws + 4262144);  // 58720256 (end 62982400)

  k0_wt<<<256, 256, 0, stream>>>(W, Wt);
  k0_wa<<<256, 64, 0, stream>>>(W, a, Wa);
  k0_adj<<<1, 64, 0, stream>>>(B, adjn);
  k1_gemm<<<1024, 256, 0, stream>>>(h, Wt, Wa, Wh, s1g, s2g);
  k2_soft<<<64, 256, 0, stream>>>(s1g, s2g, att);
  k3_out<<<16384, 256, 0, stream>>>(Wh, att, adjn, out);
}